// Round 4
// baseline (15.228 us; speedup 1.0000x reference)
//
#include <hip/hip_runtime.h>

// AdditionFFN: 4 soft byte-addition steps. Exact factorization:
//   weights(a,b,c) = pa(a)*pb(b)*pc(c)      (softmax of additive scores factorizes)
//   result_i[j]    = pc0*conv_i[j] + pc1*conv_i[(j-1)&255],  conv_i = pa_i (*) pb_i (circular)
//   P(carry)       = pc0*A_i + pc1*B_i,  A_i = P(a+b>=256), B_i = P(a+b>=255)
// Steps couple ONLY through the scalar carry -> conv_i/A_i/B_i are step-parallel.
// One block, 1024 threads, 2 barriers.
// R3 change: conv inner loop reuses the previous iteration's pa-window
// (w1(k) == w0(k-1)) -> 1 ds_read_b128 per 16 FMAs instead of 2, halving the
// dominant LDS read traffic (conv was LDS-BW-bound: 2KB/wave/iter @128B/cy).
// W1/W2 table inputs are never read.

__global__ __launch_bounds__(1024) void addffn_kernel(const float* __restrict__ a_emb,
                                                      const float* __restrict__ b_emb,
                                                      float* __restrict__ out) {
    const int tid  = threadIdx.x;
    const int wave = tid >> 6;    // 0..15
    const int lane = tid & 63;

    __shared__ __align__(16) float pa_dup[4][512];   // pa_dup[y] = pa[y & 255]
    __shared__ __align__(16) float pbs[4][256];      // pbs[x]    = pb[(x+1) & 255]
    __shared__ __align__(16) float sfx[4][260];      // sfx[k] = sum_{b>=k} pb[b], k=0..256
    __shared__ __align__(16) float cpart[4][4][256]; // [quarter][step][j] conv partials
    __shared__ float AB[4][2];                       // {A_i, B_i}

    // ---- phase 1: wave-local softmax + scan (waves 0..3; wave g = step g) ----
    if (wave < 4) {
        const int g = wave;
        const float4 a4 = *(const float4*)(a_emb + (g << 8) + 4 * lane);
        const float4 b4 = *(const float4*)(b_emb + (g << 8) + 4 * lane);
        const float ea0 = expf(10.f * a4.x), ea1 = expf(10.f * a4.y);
        const float ea2 = expf(10.f * a4.z), ea3 = expf(10.f * a4.w);
        const float eb0 = expf(10.f * b4.x), eb1 = expf(10.f * b4.y);
        const float eb2 = expf(10.f * b4.z), eb3 = expf(10.f * b4.w);

        float sa = ea0 + ea1 + ea2 + ea3;
        const float lb0 = eb0, lb1 = lb0 + eb1, lb2 = lb1 + eb2, lb3 = lb2 + eb3;

        #pragma unroll
        for (int m = 1; m < 64; m <<= 1) sa += __shfl_xor(sa, m, 64);
        float incl = lb3;
        #pragma unroll
        for (int d = 1; d < 64; d <<= 1) {
            float o = __shfl_up(incl, d, 64);
            if (lane >= d) incl += o;
        }
        const float sb   = __shfl(incl, 63, 64);
        const float excl = incl - lb3;

        const float inv_sa = 1.f / sa, inv_sb = 1.f / sb;
        const float pa0 = ea0 * inv_sa, pa1 = ea1 * inv_sa;
        const float pa2 = ea2 * inv_sa, pa3 = ea3 * inv_sa;
        const float pb0 = eb0 * inv_sb, pb1 = eb1 * inv_sb;
        const float pb2 = eb2 * inv_sb, pb3 = eb3 * inv_sb;

        const float s0 = 1.f - excl * inv_sb;
        const float s1 = 1.f - (excl + lb0) * inv_sb;
        const float s2 = 1.f - (excl + lb1) * inv_sb;
        const float s3 = 1.f - (excl + lb2) * inv_sb;

        *(float4*)(&pa_dup[g][4 * lane])       = make_float4(pa0, pa1, pa2, pa3);
        *(float4*)(&pa_dup[g][4 * lane + 256]) = make_float4(pa0, pa1, pa2, pa3);
        const float pbn = __shfl(pb0, (lane + 1) & 63, 64);  // pb[4*(lane+1)] (wraps)
        *(float4*)(&pbs[g][4 * lane]) = make_float4(pb1, pb2, pb3, pbn);
        *(float4*)(&sfx[g][4 * lane]) = make_float4(s0, s1, s2, s3);
        if (lane == 0) sfx[g][256] = 0.f;
    }
    __syncthreads();  // barrier 1

    // ---- phase 2: conv partials, all 16 waves; wave = (quarter q, step s) ----
    // conv[j] = sum_m pb[m]*pa[(j-m)&255]; lane covers j = 4*lane+r, r=0..3,
    // m-chunks m0=4k+1, k in [16q,16q+16): pbv = pb[4k+1..4k+4] (broadcast b128),
    // pa window [base..base+7] with base = 4*lane+252-4k; the high half of the
    // window (w1) equals the previous iteration's low half (w0) -> register reuse.
    {
        const int q = wave >> 2, s = wave & 3;
        const float* PA = pa_dup[s];
        const float* PB = pbs[s];
        float acc0 = 0.f, acc1 = 0.f, acc2 = 0.f, acc3 = 0.f;
        int base = 4 * lane + 252 - 64 * q;
        float4 wprev = *(const float4*)(PA + base + 4);  // w1 for first iteration
        #pragma unroll 8
        for (int k = 16 * q; k < 16 * q + 16; ++k, base -= 4) {
            const float4 pbv = *(const float4*)(PB + 4 * k);
            const float4 w0  = *(const float4*)(PA + base);
            acc0 += pbv.x * w0.w    + pbv.y * w0.z    + pbv.z * w0.y + pbv.w * w0.x;
            acc1 += pbv.x * wprev.x + pbv.y * w0.w    + pbv.z * w0.z + pbv.w * w0.y;
            acc2 += pbv.x * wprev.y + pbv.y * wprev.x + pbv.z * w0.w + pbv.w * w0.z;
            acc3 += pbv.x * wprev.z + pbv.y * wprev.y + pbv.z * wprev.x + pbv.w * w0.w;
            wprev = w0;
        }
        *(float4*)(&cpart[q][s][4 * lane]) = make_float4(acc0, acc1, acc2, acc3);
    }
    // A/B carry dots on waves 0..7 (tiny; rides along after the conv partial)
    if (wave < 8) {
        const int s = wave & 3, isB = wave >> 2;
        const float4 pa4 = *(const float4*)(&pa_dup[s][4 * lane]);
        const int kb = (isB ? 255 : 256) - 4 * lane;
        float v = pa4.x * sfx[s][kb]     + pa4.y * sfx[s][kb - 1]
                + pa4.z * sfx[s][kb - 2] + pa4.w * sfx[s][kb - 3];
        #pragma unroll
        for (int m = 1; m < 64; m <<= 1) v += __shfl_xor(v, m, 64);
        if (lane == 0) AB[s][isB] = v;
    }
    __syncthreads();  // barrier 2

    // ---- phase 3: partial-sum + scalar carry recurrence + store ----
    const int s = tid >> 8, j = tid & 255;
    float c0 = 1.f, c1 = 0.f, p0g = 0.f, p1g = 0.f;
    #pragma unroll
    for (int i = 0; i < 4; ++i) {
        const float e0 = expf(10.f * c0);
        const float e1 = expf(10.f * c1);
        const float inv = 1.f / (e0 + e1);
        const float p0 = e0 * inv, p1 = e1 * inv;
        if (i == s) { p0g = p0; p1g = p1; }
        const float P = p0 * AB[i][0] + p1 * AB[i][1];
        c0 = 1.f - P;
        c1 = P;
    }
    const int jm = (j + 255) & 255;
    const float cj = cpart[0][s][j]  + cpart[1][s][j]  + cpart[2][s][j]  + cpart[3][s][j];
    const float cm = cpart[0][s][jm] + cpart[1][s][jm] + cpart[2][s][jm] + cpart[3][s][jm];
    out[(s << 8) + j] = p0g * cj + p1g * cm;
}

extern "C" void kernel_launch(void* const* d_in, const int* in_sizes, int n_in,
                              void* d_out, int out_size, void* d_ws, size_t ws_size,
                              hipStream_t stream) {
    // inputs: 0=a_emb [4,256] f32, 1=b_emb [4,256] f32, 2=W1, 3=W2_sum, 4=W2_carry (unused)
    const float* a_emb = (const float*)d_in[0];
    const float* b_emb = (const float*)d_in[1];
    float* out = (float*)d_out;  // [4,256] f32

    addffn_kernel<<<1, 1024, 0, stream>>>(a_emb, b_emb, out);
}